// Round 3
// baseline (1215.739 us; speedup 1.0000x reference)
//
#include <hip/hip_runtime.h>

// EdgeCNN (DynamicEdgeConv): N=20000, F=64, H=128, K=6 (incl self).
// ROUND-3 FIX: inputs/outputs are FLOAT32 per the reference (jnp.float32) and the
// harness doc. Rounds 1-2 read them as bf16 -> random mantissa halves parsed as
// bf16 gave NaN/inf weights -> NaN output. All casts now float*.
// Pipeline: sq -> fused dist+top6 (ws-adaptive j-chunking) -> [merge] -> MLP+max.

#define N_NODES 20000
#define FDIM 64
#define KNN 6
#define HID 128
#define RPB 256
#define TILE_J 64
#define N_PAD 20480
#define MAX_CHUNKS 10

// Sorted-ascending 6-slot insert; strict '<' => earlier (lower-j) candidate wins
// ties, matching jax.lax.top_k stability when scanned in ascending j.
#define INSERT_CAND(dv, jv) do {                                              \
  if ((dv) < bd[5]) {                                                         \
    const bool c0 = (dv) < bd[0], c1 = (dv) < bd[1], c2 = (dv) < bd[2];       \
    const bool c3 = (dv) < bd[3], c4 = (dv) < bd[4];                          \
    bd[5] = c4 ? bd[4] : (dv);              bj[5] = c4 ? bj[4] : (jv);        \
    bd[4] = c4 ? (c3 ? bd[3] : (dv)) : bd[4]; bj[4] = c4 ? (c3 ? bj[3] : (jv)) : bj[4]; \
    bd[3] = c3 ? (c2 ? bd[2] : (dv)) : bd[3]; bj[3] = c3 ? (c2 ? bj[2] : (jv)) : bj[3]; \
    bd[2] = c2 ? (c1 ? bd[1] : (dv)) : bd[2]; bj[2] = c2 ? (c1 ? bj[1] : (jv)) : bj[2]; \
    bd[1] = c1 ? (c0 ? bd[0] : (dv)) : bd[1]; bj[1] = c1 ? (c0 ? bj[0] : (jv)) : bj[1]; \
    bd[0] = c0 ? (dv) : bd[0];              bj[0] = c0 ? (jv) : bj[0];        \
  }                                                                           \
} while (0)

__global__ void sq_kernel(const float* __restrict__ x, float* __restrict__ sq) {
  const int i = blockIdx.x * blockDim.x + threadIdx.x;
  if (i >= N_NODES) return;
  const float4* r4 = (const float4*)(x + (size_t)i * FDIM);
  float s = 0.f;
#pragma unroll
  for (int q = 0; q < 16; ++q) {
    const float4 a = r4[q];
    s = fmaf(a.x, a.x, s);
    s = fmaf(a.y, a.y, s);
    s = fmaf(a.z, a.z, s);
    s = fmaf(a.w, a.w, s);
  }
  sq[i] = s;
}

__global__ __launch_bounds__(RPB) void knn_partial_kernel(
    const float* __restrict__ x, const float* __restrict__ sq,
    float* __restrict__ cand_d, int* __restrict__ cand_j,
    int* __restrict__ knn_idx, int jchunk, int nchunks) {
  __shared__ __align__(16) float xs[TILE_J][FDIM + 4];  // +4 pad, rows stay 16B-aligned
  __shared__ float sqs[TILE_J];
  const int tid = threadIdx.x;
  const int i = blockIdx.x * RPB + tid;
  const bool valid = i < N_NODES;
  const int jc = blockIdx.y;

  float xi[FDIM];
  float sqi = 0.f;
  if (valid) {
    const float4* r4 = (const float4*)(x + (size_t)i * FDIM);
#pragma unroll
    for (int q = 0; q < 16; ++q) {
      const float4 a = r4[q];
      xi[q * 4 + 0] = a.x; xi[q * 4 + 1] = a.y;
      xi[q * 4 + 2] = a.z; xi[q * 4 + 3] = a.w;
    }
    sqi = sq[i];
  } else {
#pragma unroll
    for (int f = 0; f < FDIM; ++f) xi[f] = 0.f;
  }

  float bd[KNN];
  int bj[KNN];
#pragma unroll
  for (int k = 0; k < KNN; ++k) { bd[k] = __builtin_inff(); bj[k] = 0; }

  const int jcbase = jc * jchunk;
  for (int t0 = 0; t0 < jchunk; t0 += TILE_J) {
    const int jt = jcbase + t0;
    __syncthreads();
    {
      // 256 threads stage 64 rows x 64 f32: 4 float4 per thread.
      const int jj = tid >> 2;
      const int f0 = (tid & 3) * 16;
      const int j = jt + jj;
      float4* dst = (float4*)&xs[jj][f0];
      if (j < N_NODES) {
        const float4* src = (const float4*)(x + (size_t)j * FDIM + f0);
        dst[0] = src[0];
        dst[1] = src[1];
        dst[2] = src[2];
        dst[3] = src[3];
      } else {
        const float4 z = make_float4(0.f, 0.f, 0.f, 0.f);
        dst[0] = z; dst[1] = z; dst[2] = z; dst[3] = z;
      }
      if (tid < TILE_J) {
        const int j2 = jt + tid;
        sqs[tid] = (j2 < N_NODES) ? sq[j2] : 0.f;
      }
    }
    __syncthreads();
    const int rem = N_NODES - jt;
    const int jmax = rem < TILE_J ? rem : TILE_J;
    for (int jj = 0; jj < jmax; ++jj) {
      const float4* xr4 = (const float4*)&xs[jj][0];
      float dot = 0.f;
#pragma unroll
      for (int q = 0; q < 16; ++q) {
        const float4 v = xr4[q];
        dot = fmaf(xi[q * 4 + 0], v.x, dot);
        dot = fmaf(xi[q * 4 + 1], v.y, dot);
        dot = fmaf(xi[q * 4 + 2], v.z, dot);
        dot = fmaf(xi[q * 4 + 3], v.w, dot);
      }
      const float d = fmaf(-2.f, dot, sqi + sqs[jj]);  // sq_i + sq_j - 2*dot
      const int j = jt + jj;
      INSERT_CAND(d, j);
    }
  }

  if (valid) {
    if (nchunks == 1) {
#pragma unroll
      for (int k = 0; k < KNN; ++k) knn_idx[(size_t)i * KNN + k] = bj[k];
    } else {
#pragma unroll
      for (int k = 0; k < KNN; ++k) {
        const size_t off = ((size_t)jc * KNN + k) * N_PAD + i;
        cand_d[off] = bd[k];
        cand_j[off] = bj[k];
      }
    }
  }
}

__global__ void knn_merge_kernel(const float* __restrict__ cand_d,
                                 const int* __restrict__ cand_j,
                                 int* __restrict__ knn_idx, int nchunks) {
  const int i = blockIdx.x * blockDim.x + threadIdx.x;
  if (i >= N_NODES) return;
  float bd[KNN];
  int bj[KNN];
#pragma unroll
  for (int k = 0; k < KNN; ++k) { bd[k] = __builtin_inff(); bj[k] = 0; }
  for (int jc = 0; jc < nchunks; ++jc) {  // ascending j preserves tie-break
#pragma unroll
    for (int k = 0; k < KNN; ++k) {
      const size_t off = ((size_t)jc * KNN + k) * N_PAD + i;
      const float d = cand_d[off];
      const int j = cand_j[off];
      INSERT_CAND(d, j);
    }
  }
#pragma unroll
  for (int k = 0; k < KNN; ++k) knn_idx[(size_t)i * KNN + k] = bj[k];
}

__global__ __launch_bounds__(HID) void mlp_kernel(
    const float* __restrict__ x, const int* __restrict__ knn_idx,
    const float* __restrict__ W1, const float* __restrict__ b1,
    const float* __restrict__ W2, const float* __restrict__ b2,
    float* __restrict__ out) {
  __shared__ float xi_s[FDIM];
  __shared__ float xd_s[KNN][FDIM];
  __shared__ float h1_s[KNN][HID];
  __shared__ int nb[KNN];
  const int i = blockIdx.x;
  const int t = threadIdx.x;  // output channel
  if (t < KNN) nb[t] = knn_idx[(size_t)i * KNN + t];
  if (t < FDIM) xi_s[t] = x[(size_t)i * FDIM + t];
  __syncthreads();
  for (int e = t; e < KNN * FDIM; e += HID) {  // 3 iters/thread
    const int k = e >> 6;
    const int f = e & 63;
    xd_s[k][f] = x[(size_t)nb[k] * FDIM + f] - xi_s[f];
  }
  __syncthreads();

  // Layer 1: msg = [xi, xj-xi]; xi half shared across the 6 neighbors.
  float s0 = b1[t];
  for (int f = 0; f < FDIM; ++f) {
    const float w = W1[f * HID + t];
    s0 = fmaf(xi_s[f], w, s0);
  }
  float acc[KNN];
#pragma unroll
  for (int k = 0; k < KNN; ++k) acc[k] = s0;
  for (int f = 0; f < FDIM; ++f) {
    const float w = W1[(FDIM + f) * HID + t];
#pragma unroll
    for (int k = 0; k < KNN; ++k) acc[k] = fmaf(xd_s[k][f], w, acc[k]);
  }
#pragma unroll
  for (int k = 0; k < KNN; ++k) h1_s[k][t] = fmaxf(acc[k], 0.f);
  __syncthreads();

  // Layer 2 (no relu) + max aggregation.
  float acc2[KNN];
  const float bb = b2[t];
#pragma unroll
  for (int k = 0; k < KNN; ++k) acc2[k] = bb;
  for (int h = 0; h < HID; ++h) {
    const float w = W2[h * HID + t];
#pragma unroll
    for (int k = 0; k < KNN; ++k) acc2[k] = fmaf(h1_s[k][h], w, acc2[k]);
  }
  float m = acc2[0];
#pragma unroll
  for (int k = 1; k < KNN; ++k) m = fmaxf(m, acc2[k]);
  out[(size_t)i * HID + t] = m;
}

extern "C" void kernel_launch(void* const* d_in, const int* in_sizes, int n_in,
                              void* d_out, int out_size, void* d_ws, size_t ws_size,
                              hipStream_t stream) {
  const float* x  = (const float*)d_in[0];
  // d_in[1] = edge_index (int64): unused by the reference
  const float* W1 = (const float*)d_in[2];
  const float* b1 = (const float*)d_in[3];
  const float* W2 = (const float*)d_in[4];
  const float* b2 = (const float*)d_in[5];
  float* out = (float*)d_out;

  // ws layout: [sq: N_PAD f32][knn: N*K i32][cand_d | cand_j: nc chunks each]
  // BASE = 0x90000 (589,824 B) >= sq (81,920) + knn (480,000).
  const size_t BASE = 0x90000;
  const size_t PER_CHUNK = (size_t)KNN * N_PAD * 8;  // 983,040 B (d+j)
  int nc = 1;
  if (ws_size > BASE + PER_CHUNK) {
    size_t fit = (ws_size - BASE) / PER_CHUNK;
    nc = fit < (size_t)MAX_CHUNKS ? (int)fit : MAX_CHUNKS;
    if (nc < 1) nc = 1;
  }
  int jchunk = ((N_NODES + nc - 1) / nc + TILE_J - 1) / TILE_J * TILE_J;

  char* ws = (char*)d_ws;
  float* sq = (float*)ws;
  int* knn = (int*)(ws + (size_t)N_PAD * 4);
  float* cand_d = (float*)(ws + BASE);
  int* cand_j = (int*)(ws + BASE + (size_t)nc * KNN * N_PAD * 4);

  sq_kernel<<<dim3((N_NODES + 255) / 256), dim3(256), 0, stream>>>(x, sq);
  dim3 g((N_NODES + RPB - 1) / RPB, nc);
  knn_partial_kernel<<<g, dim3(RPB), 0, stream>>>(x, sq, cand_d, cand_j, knn,
                                                  jchunk, nc);
  if (nc > 1) {
    knn_merge_kernel<<<dim3((N_NODES + 255) / 256), dim3(256), 0, stream>>>(
        cand_d, cand_j, knn, nc);
  }
  mlp_kernel<<<dim3(N_NODES), dim3(HID), 0, stream>>>(x, knn, W1, b1, W2, b2, out);
}

// Round 4
// 1213.374 us; speedup vs baseline: 1.0019x; 1.0019x over previous
//
#include <hip/hip_runtime.h>

// EdgeCNN (DynamicEdgeConv): N=20000, F=64, H=128, K=6 (incl self). All f32.
// Pipeline: sq -> fused dist+top6 (ws-adaptive j-chunking) -> [merge] -> MLP+max.
// ROUND-4: knn_partial showed VGPR_Count=56 (< the 64 floats of xi) with zero
// scratch writes -> compiler was REMATERIALIZING xi from global x inside the
// inner loop (FETCH 33MB >> 5MB of x, 3.5x off the 326us FMA floor). Fix:
// __launch_bounds__(256,2) (register budget 256) + inline-asm register pin on
// xi[] so the allocator cannot re-load it from memory.

#define N_NODES 20000
#define FDIM 64
#define KNN 6
#define HID 128
#define RPB 256
#define TILE_J 64
#define N_PAD 20480
#define MAX_CHUNKS 10

// Sorted-ascending 6-slot insert; strict '<' => earlier (lower-j) candidate wins
// ties, matching jax.lax.top_k stability when scanned in ascending j.
#define INSERT_CAND(dv, jv) do {                                              \
  if ((dv) < bd[5]) {                                                         \
    const bool c0 = (dv) < bd[0], c1 = (dv) < bd[1], c2 = (dv) < bd[2];       \
    const bool c3 = (dv) < bd[3], c4 = (dv) < bd[4];                          \
    bd[5] = c4 ? bd[4] : (dv);              bj[5] = c4 ? bj[4] : (jv);        \
    bd[4] = c4 ? (c3 ? bd[3] : (dv)) : bd[4]; bj[4] = c4 ? (c3 ? bj[3] : (jv)) : bj[4]; \
    bd[3] = c3 ? (c2 ? bd[2] : (dv)) : bd[3]; bj[3] = c3 ? (c2 ? bj[2] : (jv)) : bj[3]; \
    bd[2] = c2 ? (c1 ? bd[1] : (dv)) : bd[2]; bj[2] = c2 ? (c1 ? bj[1] : (jv)) : bj[2]; \
    bd[1] = c1 ? (c0 ? bd[0] : (dv)) : bd[1]; bj[1] = c1 ? (c0 ? bj[0] : (jv)) : bj[1]; \
    bd[0] = c0 ? (dv) : bd[0];              bj[0] = c0 ? (jv) : bj[0];        \
  }                                                                           \
} while (0)

__global__ void sq_kernel(const float* __restrict__ x, float* __restrict__ sq) {
  const int i = blockIdx.x * blockDim.x + threadIdx.x;
  if (i >= N_NODES) return;
  const float4* r4 = (const float4*)(x + (size_t)i * FDIM);
  float s = 0.f;
#pragma unroll
  for (int q = 0; q < 16; ++q) {
    const float4 a = r4[q];
    s = fmaf(a.x, a.x, s);
    s = fmaf(a.y, a.y, s);
    s = fmaf(a.z, a.z, s);
    s = fmaf(a.w, a.w, s);
  }
  sq[i] = s;
}

__global__ __launch_bounds__(RPB, 2) void knn_partial_kernel(
    const float* __restrict__ x, const float* __restrict__ sq,
    float* __restrict__ cand_d, int* __restrict__ cand_j,
    int* __restrict__ knn_idx, int jchunk, int nchunks) {
  __shared__ __align__(16) float xs[TILE_J][FDIM + 4];  // +4 pad, rows 16B-aligned
  __shared__ float sqs[TILE_J];
  const int tid = threadIdx.x;
  const int i = blockIdx.x * RPB + tid;
  const bool valid = i < N_NODES;
  const int jc = blockIdx.y;

  float xi[FDIM];
  float sqi = 0.f;
  if (valid) {
    const float4* r4 = (const float4*)(x + (size_t)i * FDIM);
#pragma unroll
    for (int q = 0; q < 16; ++q) {
      const float4 a = r4[q];
      xi[q * 4 + 0] = a.x; xi[q * 4 + 1] = a.y;
      xi[q * 4 + 2] = a.z; xi[q * 4 + 3] = a.w;
    }
    sqi = sq[i];
  } else {
#pragma unroll
    for (int f = 0; f < FDIM; ++f) xi[f] = 0.f;
  }
  // Register pin: values become asm-defined, so the compiler can NEITHER
  // rematerialize them from global memory NOR fold them — xi stays in VGPRs.
#pragma unroll
  for (int f = 0; f < FDIM; ++f) asm volatile("" : "+v"(xi[f]));

  float bd[KNN];
  int bj[KNN];
#pragma unroll
  for (int k = 0; k < KNN; ++k) { bd[k] = __builtin_inff(); bj[k] = 0; }

  const int jcbase = jc * jchunk;
  for (int t0 = 0; t0 < jchunk; t0 += TILE_J) {
    const int jt = jcbase + t0;
    __syncthreads();
    {
      // 256 threads stage 64 rows x 64 f32: 4 float4 per thread.
      const int jj = tid >> 2;
      const int f0 = (tid & 3) * 16;
      const int j = jt + jj;
      float4* dst = (float4*)&xs[jj][f0];
      if (j < N_NODES) {
        const float4* src = (const float4*)(x + (size_t)j * FDIM + f0);
        dst[0] = src[0];
        dst[1] = src[1];
        dst[2] = src[2];
        dst[3] = src[3];
      } else {
        const float4 z = make_float4(0.f, 0.f, 0.f, 0.f);
        dst[0] = z; dst[1] = z; dst[2] = z; dst[3] = z;
      }
      if (tid < TILE_J) {
        const int j2 = jt + tid;
        sqs[tid] = (j2 < N_NODES) ? sq[j2] : 0.f;
      }
    }
    __syncthreads();
    const int rem = N_NODES - jt;
    const int jmax = rem < TILE_J ? rem : TILE_J;
    for (int jj = 0; jj < jmax; ++jj) {
      const float4* xr4 = (const float4*)&xs[jj][0];
      float dot = 0.f;
#pragma unroll
      for (int q = 0; q < 16; ++q) {
        const float4 v = xr4[q];
        dot = fmaf(xi[q * 4 + 0], v.x, dot);
        dot = fmaf(xi[q * 4 + 1], v.y, dot);
        dot = fmaf(xi[q * 4 + 2], v.z, dot);
        dot = fmaf(xi[q * 4 + 3], v.w, dot);
      }
      const float d = fmaf(-2.f, dot, sqi + sqs[jj]);  // sq_i + sq_j - 2*dot
      const int j = jt + jj;
      INSERT_CAND(d, j);
    }
  }

  if (valid) {
    if (nchunks == 1) {
#pragma unroll
      for (int k = 0; k < KNN; ++k) knn_idx[(size_t)i * KNN + k] = bj[k];
    } else {
#pragma unroll
      for (int k = 0; k < KNN; ++k) {
        const size_t off = ((size_t)jc * KNN + k) * N_PAD + i;
        cand_d[off] = bd[k];
        cand_j[off] = bj[k];
      }
    }
  }
}

__global__ void knn_merge_kernel(const float* __restrict__ cand_d,
                                 const int* __restrict__ cand_j,
                                 int* __restrict__ knn_idx, int nchunks) {
  const int i = blockIdx.x * blockDim.x + threadIdx.x;
  if (i >= N_NODES) return;
  float bd[KNN];
  int bj[KNN];
#pragma unroll
  for (int k = 0; k < KNN; ++k) { bd[k] = __builtin_inff(); bj[k] = 0; }
  for (int jc = 0; jc < nchunks; ++jc) {  // ascending j preserves tie-break
#pragma unroll
    for (int k = 0; k < KNN; ++k) {
      const size_t off = ((size_t)jc * KNN + k) * N_PAD + i;
      const float d = cand_d[off];
      const int j = cand_j[off];
      INSERT_CAND(d, j);
    }
  }
#pragma unroll
  for (int k = 0; k < KNN; ++k) knn_idx[(size_t)i * KNN + k] = bj[k];
}

__global__ __launch_bounds__(HID) void mlp_kernel(
    const float* __restrict__ x, const int* __restrict__ knn_idx,
    const float* __restrict__ W1, const float* __restrict__ b1,
    const float* __restrict__ W2, const float* __restrict__ b2,
    float* __restrict__ out) {
  __shared__ float xi_s[FDIM];
  __shared__ float xd_s[KNN][FDIM];
  __shared__ float h1_s[KNN][HID];
  __shared__ int nb[KNN];
  const int i = blockIdx.x;
  const int t = threadIdx.x;  // output channel
  if (t < KNN) nb[t] = knn_idx[(size_t)i * KNN + t];
  if (t < FDIM) xi_s[t] = x[(size_t)i * FDIM + t];
  __syncthreads();
  for (int e = t; e < KNN * FDIM; e += HID) {  // 3 iters/thread
    const int k = e >> 6;
    const int f = e & 63;
    xd_s[k][f] = x[(size_t)nb[k] * FDIM + f] - xi_s[f];
  }
  __syncthreads();

  // Layer 1: msg = [xi, xj-xi]; xi half shared across the 6 neighbors.
  float s0 = b1[t];
  for (int f = 0; f < FDIM; ++f) {
    const float w = W1[f * HID + t];
    s0 = fmaf(xi_s[f], w, s0);
  }
  float acc[KNN];
#pragma unroll
  for (int k = 0; k < KNN; ++k) acc[k] = s0;
  for (int f = 0; f < FDIM; ++f) {
    const float w = W1[(FDIM + f) * HID + t];
#pragma unroll
    for (int k = 0; k < KNN; ++k) acc[k] = fmaf(xd_s[k][f], w, acc[k]);
  }
#pragma unroll
  for (int k = 0; k < KNN; ++k) h1_s[k][t] = fmaxf(acc[k], 0.f);
  __syncthreads();

  // Layer 2 (no relu) + max aggregation.
  float acc2[KNN];
  const float bb = b2[t];
#pragma unroll
  for (int k = 0; k < KNN; ++k) acc2[k] = bb;
  for (int h = 0; h < HID; ++h) {
    const float w = W2[h * HID + t];
#pragma unroll
    for (int k = 0; k < KNN; ++k) acc2[k] = fmaf(h1_s[k][h], w, acc2[k]);
  }
  float m = acc2[0];
#pragma unroll
  for (int k = 1; k < KNN; ++k) m = fmaxf(m, acc2[k]);
  out[(size_t)i * HID + t] = m;
}

extern "C" void kernel_launch(void* const* d_in, const int* in_sizes, int n_in,
                              void* d_out, int out_size, void* d_ws, size_t ws_size,
                              hipStream_t stream) {
  const float* x  = (const float*)d_in[0];
  // d_in[1] = edge_index (int64): unused by the reference
  const float* W1 = (const float*)d_in[2];
  const float* b1 = (const float*)d_in[3];
  const float* W2 = (const float*)d_in[4];
  const float* b2 = (const float*)d_in[5];
  float* out = (float*)d_out;

  // ws layout: [sq: N_PAD f32][knn: N*K i32][cand_d | cand_j: nc chunks each]
  const size_t BASE = 0x90000;
  const size_t PER_CHUNK = (size_t)KNN * N_PAD * 8;  // 983,040 B (d+j)
  int nc = 1;
  if (ws_size > BASE + PER_CHUNK) {
    size_t fit = (ws_size - BASE) / PER_CHUNK;
    nc = fit < (size_t)MAX_CHUNKS ? (int)fit : MAX_CHUNKS;
    if (nc < 1) nc = 1;
  }
  int jchunk = ((N_NODES + nc - 1) / nc + TILE_J - 1) / TILE_J * TILE_J;

  char* ws = (char*)d_ws;
  float* sq = (float*)ws;
  int* knn = (int*)(ws + (size_t)N_PAD * 4);
  float* cand_d = (float*)(ws + BASE);
  int* cand_j = (int*)(ws + BASE + (size_t)nc * KNN * N_PAD * 4);

  sq_kernel<<<dim3((N_NODES + 255) / 256), dim3(256), 0, stream>>>(x, sq);
  dim3 g((N_NODES + RPB - 1) / RPB, nc);
  knn_partial_kernel<<<g, dim3(RPB), 0, stream>>>(x, sq, cand_d, cand_j, knn,
                                                  jchunk, nc);
  if (nc > 1) {
    knn_merge_kernel<<<dim3((N_NODES + 255) / 256), dim3(256), 0, stream>>>(
        cand_d, cand_j, knn, nc);
  }
  mlp_kernel<<<dim3(N_NODES), dim3(HID), 0, stream>>>(x, knn, W1, b1, W2, b2, out);
}